// Round 20
// baseline (599.968 us; speedup 1.0000x reference)
//
#include <hip/hip_runtime.h>

// ---------------------------------------------------------------------------
// StructureEncoder — MFMA bf16 GEMMs, CSR gather aggregation (bf16, ILP-16,
// 1 node/wave for max TLP), h stored as packed bf16 (halves aggregate-write,
// bn_stats-read, and GEMM A-fetch traffic). Single-pass CSR build.
// Round-17's fused-BN aggregate reverted (serialization killed TLP).
// (2nd resubmission: rounds 18/19 both died to the same dead-container infra
// flake before the source ever reached the machine.)
// ---------------------------------------------------------------------------

typedef __attribute__((ext_vector_type(8))) short bf16x8;
typedef __attribute__((ext_vector_type(4))) float f32x4;

__device__ inline unsigned short f2bf(float f) {
    unsigned u = __float_as_uint(f);
    unsigned r = u + 0x7FFFu + ((u >> 16) & 1u);   // RNE
    return (unsigned short)(r >> 16);
}
__device__ inline float bf2f(unsigned u16) {
    return __uint_as_float(u16 << 16);
}

__global__ void k_edetect(const int* __restrict__ ei, int n, int* __restrict__ flag) {
    if (threadIdx.x == 0 && blockIdx.x == 0) {
        int is64 = 1;
        for (int i = 0; i < 64; ++i) {
            if (ei[2 * i + 1] != 0 || (unsigned)ei[2 * i] >= (unsigned)n) { is64 = 0; break; }
        }
        *flag = is64;
    }
}

__global__ __launch_bounds__(256) void deg_count(const int* __restrict__ ei,
                                                 const int* __restrict__ eflag,
                                                 unsigned* __restrict__ deg, int e, int n) {
    int i = blockIdx.x * 256 + threadIdx.x;
    if (i >= e) return;
    int d = (*eflag) ? ei[2 * (size_t)e + 2 * (size_t)i] : ei[(size_t)e + i];
    if ((unsigned)d < (unsigned)n) atomicAdd(&deg[d], 1u);
}

__global__ __launch_bounds__(256) void node_init(const unsigned* __restrict__ deg,
                                                 float* __restrict__ dis,
                                                 unsigned* __restrict__ starts,
                                                 unsigned* __restrict__ cursor,
                                                 unsigned* __restrict__ total, int n) {
    int i = blockIdx.x * 256 + threadIdx.x;
    if (i < n) {
        unsigned d = deg[i];
        dis[i] = rsqrtf((float)d + 1.0f);          // degree with self loop
        unsigned s = atomicAdd(total, d);
        starts[i] = s;
        cursor[i] = s;
    }
}

__global__ __launch_bounds__(256) void csr_fill(const int* __restrict__ ei,
                                                const int* __restrict__ eflag,
                                                unsigned* __restrict__ cursor,
                                                int* __restrict__ csr_src, int e, int n) {
    int i = blockIdx.x * 256 + threadIdx.x;
    if (i >= e) return;
    int s, d;
    if (*eflag) {
        s = ei[2 * (size_t)i];
        d = ei[2 * (size_t)e + 2 * (size_t)i];
    } else {
        s = ei[i];
        d = ei[(size_t)e + i];
    }
    if ((unsigned)s >= (unsigned)n || (unsigned)d >= (unsigned)n) return;
    unsigned slot = atomicAdd(&cursor[d], 1u);
    if (slot < (unsigned)e) csr_src[slot] = s;
}

// ---- weight prep: Wt[c][k] = bf16(W[k][c]) for W1, W2, [Wmu|Wlv]; bcat -----

__global__ __launch_bounds__(256) void prep_weights(const float* __restrict__ W1,
                                                    const float* __restrict__ W2,
                                                    const float* __restrict__ Wmu,
                                                    const float* __restrict__ Wlv,
                                                    const float* __restrict__ bmu,
                                                    const float* __restrict__ blv,
                                                    unsigned short* __restrict__ Wt1,
                                                    unsigned short* __restrict__ Wt2,
                                                    unsigned short* __restrict__ Wtc,
                                                    float* __restrict__ bcat) {
    int idx = blockIdx.x * 256 + threadIdx.x;
    if (idx < 16384) {
        int c = idx >> 7, k = idx & 127;
        Wt1[idx] = f2bf(W1[(size_t)k * 128 + c]);
    } else if (idx < 32768) {
        int t = idx - 16384, c = t >> 7, k = t & 127;
        Wt2[t] = f2bf(W2[(size_t)k * 128 + c]);
    } else if (idx < 49152) {
        int t = idx - 32768, c = t >> 7, k = t & 127;
        float v = (c < 64) ? Wmu[(size_t)k * 64 + c] : Wlv[(size_t)k * 64 + (c - 64)];
        Wtc[t] = f2bf(v);
    }
    if (idx < 128) bcat[idx] = (idx < 64) ? bmu[idx] : blv[idx - 64];
}

// ---- aggregation (gather, bf16 in AND out, ILP-16/8/4/1): 1 node/wave ------
// outh[node] (bf16x2) = bf16( dis[n]*sum dis[s]*hW[s] + dis[n]^2*hW[n] + b )

__global__ __launch_bounds__(256) void aggregate(const unsigned* __restrict__ hWb,
                                                 const int* __restrict__ csr_src,
                                                 const unsigned* __restrict__ starts,
                                                 const unsigned* __restrict__ deg,
                                                 const float* __restrict__ dis,
                                                 const float* __restrict__ bias,
                                                 unsigned* __restrict__ outh, int n) {
    int node = blockIdx.x * 4 + (threadIdx.x >> 6);
    int lane = threadIdx.x & 63;
    if (node >= n) return;
    unsigned s0 = starts[node], dn = deg[node];
    float ax = 0.f, ay = 0.f;
    unsigned j = 0;
    for (; j + 16 <= dn; j += 16) {
        int si[16]; unsigned vv[16]; float ww[16];
#pragma unroll
        for (int q = 0; q < 16; ++q) si[q] = csr_src[s0 + j + q];
#pragma unroll
        for (int q = 0; q < 16; ++q) vv[q] = hWb[(size_t)si[q] * 64 + lane];
#pragma unroll
        for (int q = 0; q < 16; ++q) ww[q] = dis[si[q]];
#pragma unroll
        for (int q = 0; q < 16; ++q) {
            ax = fmaf(bf2f(vv[q] & 0xFFFFu), ww[q], ax);
            ay = fmaf(bf2f(vv[q] >> 16), ww[q], ay);
        }
    }
    for (; j + 8 <= dn; j += 8) {
        int si[8]; unsigned vv[8]; float ww[8];
#pragma unroll
        for (int q = 0; q < 8; ++q) si[q] = csr_src[s0 + j + q];
#pragma unroll
        for (int q = 0; q < 8; ++q) vv[q] = hWb[(size_t)si[q] * 64 + lane];
#pragma unroll
        for (int q = 0; q < 8; ++q) ww[q] = dis[si[q]];
#pragma unroll
        for (int q = 0; q < 8; ++q) {
            ax = fmaf(bf2f(vv[q] & 0xFFFFu), ww[q], ax);
            ay = fmaf(bf2f(vv[q] >> 16), ww[q], ay);
        }
    }
    for (; j + 4 <= dn; j += 4) {
        int si[4]; unsigned vv[4]; float ww[4];
#pragma unroll
        for (int q = 0; q < 4; ++q) si[q] = csr_src[s0 + j + q];
#pragma unroll
        for (int q = 0; q < 4; ++q) vv[q] = hWb[(size_t)si[q] * 64 + lane];
#pragma unroll
        for (int q = 0; q < 4; ++q) ww[q] = dis[si[q]];
#pragma unroll
        for (int q = 0; q < 4; ++q) {
            ax = fmaf(bf2f(vv[q] & 0xFFFFu), ww[q], ax);
            ay = fmaf(bf2f(vv[q] >> 16), ww[q], ay);
        }
    }
    for (; j < dn; ++j) {
        int      s = csr_src[s0 + j];
        float    w = dis[s];
        unsigned v = hWb[(size_t)s * 64 + lane];
        ax = fmaf(bf2f(v & 0xFFFFu), w, ax);
        ay = fmaf(bf2f(v >> 16), w, ay);
    }
    float dii = dis[node];
    unsigned vs = hWb[(size_t)node * 64 + lane];
    float rx = fmaf(dii, ax, dii * dii * bf2f(vs & 0xFFFFu)) + bias[lane * 2];
    float ry = fmaf(dii, ay, dii * dii * bf2f(vs >> 16)) + bias[lane * 2 + 1];
    outh[(size_t)node * 64 + lane] = (unsigned)f2bf(rx) | ((unsigned)f2bf(ry) << 16);
}

// ---- BatchNorm statistics (reads packed bf16 h) ----------------------------

__global__ __launch_bounds__(256) void bn_stats(const unsigned short* __restrict__ h,
                                                float* __restrict__ sums, int n) {
    int tid = threadIdx.x;
    int c = tid & 127, half = tid >> 7;
    float s = 0.f, s2 = 0.f;
    for (int r = blockIdx.x * 2 + half; r < n; r += gridDim.x * 2) {
        float v = bf2f(h[(size_t)r * 128 + c]);
        s += v;
        s2 = fmaf(v, v, s2);
    }
    __shared__ float sh[256];
    sh[tid] = s;
    __syncthreads();
    if (tid < 128) atomicAdd(&sums[tid], sh[tid] + sh[tid + 128]);
    __syncthreads();
    sh[tid] = s2;
    __syncthreads();
    if (tid < 128) atomicAdd(&sums[128 + tid], sh[tid] + sh[tid + 128]);
}

__global__ void bn_final(const float* __restrict__ sums, const float* __restrict__ g,
                         const float* __restrict__ be, float* __restrict__ bnp, int n) {
    int c = threadIdx.x;                            // 128 threads
    float inv_n = 1.0f / (float)n;
    float mean = sums[c] * inv_n;
    float var  = sums[128 + c] * inv_n - mean * mean;
    float sc   = g[c] * rsqrtf(var + 1e-5f);
    bnp[c]       = sc;
    bnp[128 + c] = be[c] - mean * sc;
}

// ---- MFMA GEMM: C[M,128] = bnrelu(A)[M,128] @ W[128,128] -------------------
// ABF16: A is packed bf16 rows (layer2/head); else fp32 (layer1, x input).

template <bool HEAD, bool ABF16>
__global__ __launch_bounds__(256, 4) void gemm_mfma(const void* __restrict__ Av,
                                                    const unsigned short* __restrict__ Wt,
                                                    const float* __restrict__ bnp,
                                                    const float* __restrict__ bias,
                                                    void* __restrict__ Cv, int nrows) {
    __shared__ float Cl[64][130];
    __shared__ float bnsc[128], bnsh[128];

    const int tid  = threadIdx.x;
    const int lane = tid & 63;
    const int wv   = tid >> 6;
    const int rowbase = blockIdx.x * 64;
    const bool has_bn = (bnp != nullptr);
    if (has_bn && tid < 128) {
        bnsc[tid] = bnp[tid];
        bnsh[tid] = bnp[128 + tid];
    }
    __syncthreads();

    const int ar = rowbase + wv * 16 + (lane & 15);
    const int kg = (lane >> 4) * 8;
    const int bc = lane & 15;

    f32x4 acc[8];
#pragma unroll
    for (int t = 0; t < 8; ++t) acc[t] = {0.f, 0.f, 0.f, 0.f};

#pragma unroll
    for (int k0 = 0; k0 < 128; k0 += 32) {
        float va[8];
        if (ar < nrows) {
            if constexpr (ABF16) {
                const unsigned short* A = (const unsigned short*)Av;
                ushort4 r0 = *(const ushort4*)(A + (size_t)ar * 128 + k0 + kg);
                ushort4 r1 = *(const ushort4*)(A + (size_t)ar * 128 + k0 + kg + 4);
                va[0] = bf2f(r0.x); va[1] = bf2f(r0.y); va[2] = bf2f(r0.z); va[3] = bf2f(r0.w);
                va[4] = bf2f(r1.x); va[5] = bf2f(r1.y); va[6] = bf2f(r1.z); va[7] = bf2f(r1.w);
            } else {
                const float* A = (const float*)Av;
                float4 a0 = *(const float4*)(A + (size_t)ar * 128 + k0 + kg);
                float4 a1 = *(const float4*)(A + (size_t)ar * 128 + k0 + kg + 4);
                va[0] = a0.x; va[1] = a0.y; va[2] = a0.z; va[3] = a0.w;
                va[4] = a1.x; va[5] = a1.y; va[6] = a1.z; va[7] = a1.w;
            }
        } else {
#pragma unroll
            for (int i = 0; i < 8; ++i) va[i] = 0.f;
        }
        if (has_bn) {
#pragma unroll
            for (int i = 0; i < 8; ++i) {
                int k = k0 + kg + i;
                va[i] = fmaxf(0.f, fmaf(va[i], bnsc[k], bnsh[k]));
            }
        }
        bf16x8 af;
#pragma unroll
        for (int i = 0; i < 8; ++i) af[i] = (short)f2bf(va[i]);

#pragma unroll
        for (int ct = 0; ct < 8; ++ct) {
            bf16x8 bf = *(const bf16x8*)(Wt + (size_t)(ct * 16 + bc) * 128 + k0 + kg);
            acc[ct] = __builtin_amdgcn_mfma_f32_16x16x32_bf16(af, bf, acc[ct], 0, 0, 0);
        }
    }

    const int lr = wv * 16 + ((lane >> 4) << 2);
#pragma unroll
    for (int ct = 0; ct < 8; ++ct)
#pragma unroll
        for (int r = 0; r < 4; ++r)
            Cl[lr + r][ct * 16 + bc] = acc[ct][r];
    __syncthreads();

    const int row = tid >> 2;
    const int c0  = (tid & 3) * 32;
    const int gr  = rowbase + row;
    if (gr < nrows) {
        if (!HEAD) {
            unsigned* C = (unsigned*)Cv;
#pragma unroll
            for (int u = 0; u < 4; ++u) {
                int cb = c0 + u * 8;
                unsigned o0 = (unsigned)f2bf(Cl[row][cb + 0]) | ((unsigned)f2bf(Cl[row][cb + 1]) << 16);
                unsigned o1 = (unsigned)f2bf(Cl[row][cb + 2]) | ((unsigned)f2bf(Cl[row][cb + 3]) << 16);
                unsigned o2 = (unsigned)f2bf(Cl[row][cb + 4]) | ((unsigned)f2bf(Cl[row][cb + 5]) << 16);
                unsigned o3 = (unsigned)f2bf(Cl[row][cb + 6]) | ((unsigned)f2bf(Cl[row][cb + 7]) << 16);
                uint4 o4 = {o0, o1, o2, o3};
                *(uint4*)(C + (size_t)gr * 64 + cb / 2) = o4;
            }
        } else {
            float* mu = (float*)Cv;
            float* lv = mu + (size_t)nrows * 64;
            float* dst = (c0 < 64) ? (mu + (size_t)gr * 64 + c0) : (lv + (size_t)gr * 64 + (c0 - 64));
#pragma unroll
            for (int u = 0; u < 8; ++u) {
                int cb = c0 + u * 4;
                float4 o = make_float4(Cl[row][cb + 0] + bias[cb + 0],
                                       Cl[row][cb + 1] + bias[cb + 1],
                                       Cl[row][cb + 2] + bias[cb + 2],
                                       Cl[row][cb + 3] + bias[cb + 3]);
                *(float4*)(dst + u * 4) = o;
            }
        }
    }
}

// ---------------------------------------------------------------------------

extern "C" void kernel_launch(void* const* d_in, const int* in_sizes, int n_in,
                              void* d_out, int out_size, void* d_ws, size_t ws_size,
                              hipStream_t stream) {
    const float* x   = (const float*)d_in[0];
    const int*   ei  = (const int*)d_in[1];
    const float* W1  = (const float*)d_in[2];
    const float* b1  = (const float*)d_in[3];
    const float* g1  = (const float*)d_in[4];
    const float* be1 = (const float*)d_in[5];
    const float* W2  = (const float*)d_in[6];
    const float* b2  = (const float*)d_in[7];
    const float* g2  = (const float*)d_in[8];
    const float* be2 = (const float*)d_in[9];
    const float* Wmu = (const float*)d_in[10];
    const float* bmu = (const float*)d_in[11];
    const float* Wlv = (const float*)d_in[12];
    const float* blv = (const float*)d_in[13];

    const int n = in_sizes[0] / 128;   // 100000
    const int e = in_sizes[1] / 2;     // 1600000

    char* ws = (char*)d_ws;
    size_t off = 0;
    auto alloc = [&](size_t bytes) {
        void* p = ws + off;
        off = (off + bytes + 255) & ~(size_t)255;
        return p;
    };
    unsigned*       hB      = (unsigned*)alloc((size_t)n * 64 * 4);   // bf16x2 h
    unsigned*       hWb     = (unsigned*)alloc((size_t)n * 64 * 4);   // bf16x2 hW
    int*            csr_src = (int*)alloc((size_t)e * 4);
    unsigned*       deg     = (unsigned*)alloc((size_t)n * 4);
    float*          dis     = (float*)alloc((size_t)n * 4);
    unsigned*       starts  = (unsigned*)alloc((size_t)n * 4);
    unsigned*       cursor  = (unsigned*)alloc((size_t)n * 4);
    unsigned*       total   = (unsigned*)alloc(256);
    int*            eflag   = (int*)alloc(256);
    float*          sums    = (float*)alloc(256 * 4);
    float*          bnp     = (float*)alloc(256 * 4);
    unsigned short* Wt1     = (unsigned short*)alloc(16384 * 2);
    unsigned short* Wt2     = (unsigned short*)alloc(16384 * 2);
    unsigned short* Wtc     = (unsigned short*)alloc(16384 * 2);
    float*          bcat    = (float*)alloc(128 * 4);
    // ws total ~60 MB

    const int eb = (e + 255) / 256;
    const int nb = (n + 255) / 256;
    const int ab = (n + 3) / 4;
    const int gg = (n + 63) / 64;

    // prep: weights, graph CSR (single-pass, node-cursor)
    hipMemsetAsync(deg, 0, (size_t)n * 4, stream);
    hipMemsetAsync(total, 0, 4, stream);
    prep_weights<<<192, 256, 0, stream>>>(W1, W2, Wmu, Wlv, bmu, blv, Wt1, Wt2, Wtc, bcat);
    k_edetect<<<1, 64, 0, stream>>>(ei, n, eflag);
    deg_count<<<eb, 256, 0, stream>>>(ei, eflag, deg, e, n);
    node_init<<<nb, 256, 0, stream>>>(deg, dis, starts, cursor, total, n);
    csr_fill<<<eb, 256, 0, stream>>>(ei, eflag, cursor, csr_src, e, n);

    // layer 1: hW1 = x@W1 -> hWb ; h1 = agg+b1 -> hB (bf16) ; bn1
    gemm_mfma<false, false><<<gg, 256, 0, stream>>>(x, Wt1, nullptr, nullptr, hWb, n);
    aggregate<<<ab, 256, 0, stream>>>(hWb, csr_src, starts, deg, dis, b1, hB, n);
    hipMemsetAsync(sums, 0, 1024, stream);
    bn_stats<<<512, 256, 0, stream>>>((const unsigned short*)hB, sums, n);
    bn_final<<<1, 128, 0, stream>>>(sums, g1, be1, bnp, n);

    // layer 2: hW2 = bnrelu(h1)@W2 -> hWb ; h2 = agg+b2 -> hB ; bn2
    gemm_mfma<false, true><<<gg, 256, 0, stream>>>(hB, Wt2, bnp, nullptr, hWb, n);
    aggregate<<<ab, 256, 0, stream>>>(hWb, csr_src, starts, deg, dis, b2, hB, n);
    hipMemsetAsync(sums, 0, 1024, stream);
    bn_stats<<<512, 256, 0, stream>>>((const unsigned short*)hB, sums, n);
    bn_final<<<1, 128, 0, stream>>>(sums, g2, be2, bnp, n);

    // heads: bnrelu(h2)@[Wmu|Wlv]+[bmu|blv] -> d_out (mu||lv) directly
    gemm_mfma<true, true><<<gg, 256, 0, stream>>>(hB, Wtc, bnp, bcat, d_out, n);
}

// Round 22
// 447.481 us; speedup vs baseline: 1.3408x; 1.3408x over previous
//
#include <hip/hip_runtime.h>

// ---------------------------------------------------------------------------
// StructureEncoder — MFMA bf16 GEMMs, CSR gather aggregation (bf16 hW, ILP-16,
// fp32 h: r20 showed bf16-h regresses), and a block-radix CSR build with NO
// global atomics (r15 csr_fill had 16x HBM write amplification from cross-XCD
// 4B scatters; r16 bucket build had global-cursor contention; this build does
// per-block LDS cursors + one-block-per-partition final scatter).
// (Resubmission: round-21 bench was a dead-container infra flake, never ran.)
// ---------------------------------------------------------------------------

typedef __attribute__((ext_vector_type(8))) short bf16x8;
typedef __attribute__((ext_vector_type(4))) float f32x4;

#define NB   256        // histogram/stage blocks
#define PSZ  256        // nodes per partition
#define PMAX 512        // LDS capacity for partition arrays (P=391 for n=1e5)

__device__ inline unsigned short f2bf(float f) {
    unsigned u = __float_as_uint(f);
    unsigned r = u + 0x7FFFu + ((u >> 16) & 1u);   // RNE
    return (unsigned short)(r >> 16);
}
__device__ inline float bf2f(unsigned u16) {
    return __uint_as_float(u16 << 16);
}

__global__ void k_edetect(const int* __restrict__ ei, int n, int* __restrict__ flag) {
    if (threadIdx.x == 0 && blockIdx.x == 0) {
        int is64 = 1;
        for (int i = 0; i < 64; ++i) {
            if (ei[2 * i + 1] != 0 || (unsigned)ei[2 * i] >= (unsigned)n) { is64 = 0; break; }
        }
        *flag = is64;
    }
}

__device__ inline void load_edge(const int* __restrict__ ei, int eflag, size_t i, size_t e,
                                 int& s, int& d) {
    if (eflag) {
        s = ei[2 * i];
        d = ei[2 * e + 2 * i];
    } else {
        s = ei[i];
        d = ei[e + i];
    }
}

// ---- phase 1: per-block partition histogram gh[p][b] -----------------------

__global__ __launch_bounds__(256) void k_hist(const int* __restrict__ ei,
                                              const int* __restrict__ eflag,
                                              unsigned* __restrict__ gh,
                                              int e, int n, int P, int epb) {
    __shared__ unsigned hist[PMAX];
    int t = threadIdx.x, b = blockIdx.x;
    for (int p = t; p < P; p += 256) hist[p] = 0u;
    __syncthreads();
    int f = *eflag;
    int end = min(e, (b + 1) * epb);
    for (int i = b * epb + t; i < end; i += 256) {
        int s, d;
        load_edge(ei, f, (size_t)i, (size_t)e, s, d);
        if ((unsigned)d < (unsigned)n) atomicAdd(&hist[d >> 8], 1u);
    }
    __syncthreads();
    for (int p = t; p < P; p += 256) gh[(size_t)p * NB + b] = hist[p];
}

// ---- phase 2a: per-partition exclusive scan over blocks --------------------

__global__ __launch_bounds__(256) void k_scanp(const unsigned* __restrict__ gh,
                                               unsigned* __restrict__ boffs,
                                               unsigned* __restrict__ tot, int P) {
    __shared__ unsigned tmp[256];
    int p = blockIdx.x, t = threadIdx.x;
    unsigned v = gh[(size_t)p * NB + t];
    tmp[t] = v;
    __syncthreads();
    for (int o = 1; o < 256; o <<= 1) {
        unsigned u = (t >= o) ? tmp[t - o] : 0u;
        __syncthreads();
        tmp[t] += u;
        __syncthreads();
    }
    boffs[(size_t)p * NB + t] = tmp[t] - v;
    if (t == 255) tot[p] = tmp[255];
}

// ---- phase 2b: exclusive scan of partition totals -> gofs ------------------

__global__ void k_scant(const unsigned* __restrict__ tot,
                        unsigned* __restrict__ gofs, int P) {
    __shared__ unsigned tmp[512];
    int t = threadIdx.x;                  // 512 threads
    unsigned v = (t < P) ? tot[t] : 0u;
    tmp[t] = v;
    __syncthreads();
    for (int o = 1; o < 512; o <<= 1) {
        unsigned u = (t >= o) ? tmp[t - o] : 0u;
        __syncthreads();
        tmp[t] += u;
        __syncthreads();
    }
    if (t < P) gofs[t] = tmp[t] - v;
}

// ---- phase 3: stage edges grouped by partition (LDS cursors, no glb atomics)

__global__ __launch_bounds__(256) void k_stage(const int* __restrict__ ei,
                                               const int* __restrict__ eflag,
                                               const unsigned* __restrict__ boffs,
                                               const unsigned* __restrict__ gofs,
                                               uint2* __restrict__ staged,
                                               int e, int n, int P, int epb) {
    __shared__ unsigned cur[PMAX];
    int t = threadIdx.x, b = blockIdx.x;
    for (int p = t; p < P; p += 256) cur[p] = gofs[p] + boffs[(size_t)p * NB + b];
    __syncthreads();
    int f = *eflag;
    int end = min(e, (b + 1) * epb);
    for (int i = b * epb + t; i < end; i += 256) {
        int s, d;
        load_edge(ei, f, (size_t)i, (size_t)e, s, d);
        if ((unsigned)d >= (unsigned)n) continue;
        unsigned pos = atomicAdd(&cur[d >> 8], 1u);
        if (pos < (unsigned)e) staged[pos] = make_uint2((unsigned)s, (unsigned)d);
    }
}

// ---- phase 4: one block per partition: deg/dis/starts + csr scatter --------

__global__ __launch_bounds__(256) void k_fill(const uint2* __restrict__ staged,
                                              const unsigned* __restrict__ gofs,
                                              const unsigned* __restrict__ tot,
                                              int* __restrict__ csr_src,
                                              unsigned* __restrict__ deg,
                                              float* __restrict__ dis,
                                              unsigned* __restrict__ starts,
                                              int n, int P) {
    __shared__ unsigned h2[256], tmp[256], cur2[256];
    int p = blockIdx.x, t = threadIdx.x;
    unsigned base = gofs[p], cnt = tot[p];
    h2[t] = 0u;
    __syncthreads();
    for (unsigned i = t; i < cnt; i += 256) {
        unsigned dl = staged[base + i].y & 255u;
        atomicAdd(&h2[dl], 1u);
    }
    __syncthreads();
    unsigned cv = h2[t];
    tmp[t] = cv;
    __syncthreads();
    for (int o = 1; o < 256; o <<= 1) {
        unsigned u = (t >= o) ? tmp[t - o] : 0u;
        __syncthreads();
        tmp[t] += u;
        __syncthreads();
    }
    unsigned excl = tmp[t] - cv;
    int node = p * PSZ + t;
    if (node < n) {
        deg[node]    = cv;
        dis[node]    = rsqrtf((float)cv + 1.0f);   // degree with self loop
        starts[node] = base + excl;
    }
    cur2[t] = base + excl;
    __syncthreads();
    for (unsigned i = t; i < cnt; i += 256) {
        uint2 ed = staged[base + i];
        unsigned slot = atomicAdd(&cur2[ed.y & 255u], 1u);
        csr_src[slot] = (ed.x < (unsigned)n) ? (int)ed.x : 0;
    }
}

// ---- weight prep: Wt[c][k] = bf16(W[k][c]) for W1, W2, [Wmu|Wlv]; bcat -----

__global__ __launch_bounds__(256) void prep_weights(const float* __restrict__ W1,
                                                    const float* __restrict__ W2,
                                                    const float* __restrict__ Wmu,
                                                    const float* __restrict__ Wlv,
                                                    const float* __restrict__ bmu,
                                                    const float* __restrict__ blv,
                                                    unsigned short* __restrict__ Wt1,
                                                    unsigned short* __restrict__ Wt2,
                                                    unsigned short* __restrict__ Wtc,
                                                    float* __restrict__ bcat) {
    int idx = blockIdx.x * 256 + threadIdx.x;
    if (idx < 16384) {
        int c = idx >> 7, k = idx & 127;
        Wt1[idx] = f2bf(W1[(size_t)k * 128 + c]);
    } else if (idx < 32768) {
        int t = idx - 16384, c = t >> 7, k = t & 127;
        Wt2[t] = f2bf(W2[(size_t)k * 128 + c]);
    } else if (idx < 49152) {
        int t = idx - 32768, c = t >> 7, k = t & 127;
        float v = (c < 64) ? Wmu[(size_t)k * 64 + c] : Wlv[(size_t)k * 64 + (c - 64)];
        Wtc[t] = f2bf(v);
    }
    if (idx < 128) bcat[idx] = (idx < 64) ? bmu[idx] : blv[idx - 64];
}

// ---- aggregation (gather, bf16 hW in, fp32 h out, ILP-16/8/4/1) ------------

__global__ __launch_bounds__(256) void aggregate(const unsigned* __restrict__ hWb,
                                                 const int* __restrict__ csr_src,
                                                 const unsigned* __restrict__ starts,
                                                 const unsigned* __restrict__ deg,
                                                 const float* __restrict__ dis,
                                                 const float* __restrict__ bias,
                                                 float* __restrict__ outh, int n) {
    int node = blockIdx.x * 4 + (threadIdx.x >> 6);
    int lane = threadIdx.x & 63;
    if (node >= n) return;
    unsigned s0 = starts[node], dn = deg[node];
    float ax = 0.f, ay = 0.f;
    unsigned j = 0;
    for (; j + 16 <= dn; j += 16) {
        int si[16]; unsigned vv[16]; float ww[16];
#pragma unroll
        for (int q = 0; q < 16; ++q) si[q] = csr_src[s0 + j + q];
#pragma unroll
        for (int q = 0; q < 16; ++q) vv[q] = hWb[(size_t)si[q] * 64 + lane];
#pragma unroll
        for (int q = 0; q < 16; ++q) ww[q] = dis[si[q]];
#pragma unroll
        for (int q = 0; q < 16; ++q) {
            ax = fmaf(bf2f(vv[q] & 0xFFFFu), ww[q], ax);
            ay = fmaf(bf2f(vv[q] >> 16), ww[q], ay);
        }
    }
    for (; j + 8 <= dn; j += 8) {
        int si[8]; unsigned vv[8]; float ww[8];
#pragma unroll
        for (int q = 0; q < 8; ++q) si[q] = csr_src[s0 + j + q];
#pragma unroll
        for (int q = 0; q < 8; ++q) vv[q] = hWb[(size_t)si[q] * 64 + lane];
#pragma unroll
        for (int q = 0; q < 8; ++q) ww[q] = dis[si[q]];
#pragma unroll
        for (int q = 0; q < 8; ++q) {
            ax = fmaf(bf2f(vv[q] & 0xFFFFu), ww[q], ax);
            ay = fmaf(bf2f(vv[q] >> 16), ww[q], ay);
        }
    }
    for (; j + 4 <= dn; j += 4) {
        int si[4]; unsigned vv[4]; float ww[4];
#pragma unroll
        for (int q = 0; q < 4; ++q) si[q] = csr_src[s0 + j + q];
#pragma unroll
        for (int q = 0; q < 4; ++q) vv[q] = hWb[(size_t)si[q] * 64 + lane];
#pragma unroll
        for (int q = 0; q < 4; ++q) ww[q] = dis[si[q]];
#pragma unroll
        for (int q = 0; q < 4; ++q) {
            ax = fmaf(bf2f(vv[q] & 0xFFFFu), ww[q], ax);
            ay = fmaf(bf2f(vv[q] >> 16), ww[q], ay);
        }
    }
    for (; j < dn; ++j) {
        int      s = csr_src[s0 + j];
        float    w = dis[s];
        unsigned v = hWb[(size_t)s * 64 + lane];
        ax = fmaf(bf2f(v & 0xFFFFu), w, ax);
        ay = fmaf(bf2f(v >> 16), w, ay);
    }
    float dii = dis[node];
    unsigned vs = hWb[(size_t)node * 64 + lane];
    float rx = fmaf(dii, ax, dii * dii * bf2f(vs & 0xFFFFu)) + bias[lane * 2];
    float ry = fmaf(dii, ay, dii * dii * bf2f(vs >> 16)) + bias[lane * 2 + 1];
    *(float2*)(outh + (size_t)node * 128 + lane * 2) = make_float2(rx, ry);
}

// ---- BatchNorm statistics (fp32 h) -----------------------------------------

__global__ __launch_bounds__(256) void bn_stats(const float* __restrict__ h,
                                                float* __restrict__ sums, int n) {
    int tid = threadIdx.x;
    int c = tid & 127, half = tid >> 7;
    float s = 0.f, s2 = 0.f;
    for (int r = blockIdx.x * 2 + half; r < n; r += gridDim.x * 2) {
        float v = h[(size_t)r * 128 + c];
        s += v;
        s2 = fmaf(v, v, s2);
    }
    __shared__ float sh[256];
    sh[tid] = s;
    __syncthreads();
    if (tid < 128) atomicAdd(&sums[tid], sh[tid] + sh[tid + 128]);
    __syncthreads();
    sh[tid] = s2;
    __syncthreads();
    if (tid < 128) atomicAdd(&sums[128 + tid], sh[tid] + sh[tid + 128]);
}

__global__ void bn_final(const float* __restrict__ sums, const float* __restrict__ g,
                         const float* __restrict__ be, float* __restrict__ bnp, int n) {
    int c = threadIdx.x;                            // 128 threads
    float inv_n = 1.0f / (float)n;
    float mean = sums[c] * inv_n;
    float var  = sums[128 + c] * inv_n - mean * mean;
    float sc   = g[c] * rsqrtf(var + 1e-5f);
    bnp[c]       = sc;
    bnp[128 + c] = be[c] - mean * sc;
}

// ---- MFMA GEMM: C[M,128] = bnrelu(A)[M,128] @ W[128,128], A fp32 -----------

template <bool HEAD>
__global__ __launch_bounds__(256, 4) void gemm_mfma(const float* __restrict__ A,
                                                    const unsigned short* __restrict__ Wt,
                                                    const float* __restrict__ bnp,
                                                    const float* __restrict__ bias,
                                                    void* __restrict__ Cv, int nrows) {
    __shared__ float Cl[64][130];
    __shared__ float bnsc[128], bnsh[128];

    const int tid  = threadIdx.x;
    const int lane = tid & 63;
    const int wv   = tid >> 6;
    const int rowbase = blockIdx.x * 64;
    const bool has_bn = (bnp != nullptr);
    if (has_bn && tid < 128) {
        bnsc[tid] = bnp[tid];
        bnsh[tid] = bnp[128 + tid];
    }
    __syncthreads();

    const int ar = rowbase + wv * 16 + (lane & 15);
    const int kg = (lane >> 4) * 8;
    const int bc = lane & 15;

    f32x4 acc[8];
#pragma unroll
    for (int t = 0; t < 8; ++t) acc[t] = {0.f, 0.f, 0.f, 0.f};

#pragma unroll
    for (int k0 = 0; k0 < 128; k0 += 32) {
        float va[8];
        if (ar < nrows) {
            float4 a0 = *(const float4*)(A + (size_t)ar * 128 + k0 + kg);
            float4 a1 = *(const float4*)(A + (size_t)ar * 128 + k0 + kg + 4);
            va[0] = a0.x; va[1] = a0.y; va[2] = a0.z; va[3] = a0.w;
            va[4] = a1.x; va[5] = a1.y; va[6] = a1.z; va[7] = a1.w;
        } else {
#pragma unroll
            for (int i = 0; i < 8; ++i) va[i] = 0.f;
        }
        if (has_bn) {
#pragma unroll
            for (int i = 0; i < 8; ++i) {
                int k = k0 + kg + i;
                va[i] = fmaxf(0.f, fmaf(va[i], bnsc[k], bnsh[k]));
            }
        }
        bf16x8 af;
#pragma unroll
        for (int i = 0; i < 8; ++i) af[i] = (short)f2bf(va[i]);

#pragma unroll
        for (int ct = 0; ct < 8; ++ct) {
            bf16x8 bf = *(const bf16x8*)(Wt + (size_t)(ct * 16 + bc) * 128 + k0 + kg);
            acc[ct] = __builtin_amdgcn_mfma_f32_16x16x32_bf16(af, bf, acc[ct], 0, 0, 0);
        }
    }

    const int lr = wv * 16 + ((lane >> 4) << 2);
#pragma unroll
    for (int ct = 0; ct < 8; ++ct)
#pragma unroll
        for (int r = 0; r < 4; ++r)
            Cl[lr + r][ct * 16 + bc] = acc[ct][r];
    __syncthreads();

    const int row = tid >> 2;
    const int c0  = (tid & 3) * 32;
    const int gr  = rowbase + row;
    if (gr < nrows) {
        if (!HEAD) {
            unsigned* C = (unsigned*)Cv;
#pragma unroll
            for (int u = 0; u < 4; ++u) {
                int cb = c0 + u * 8;
                unsigned o0 = (unsigned)f2bf(Cl[row][cb + 0]) | ((unsigned)f2bf(Cl[row][cb + 1]) << 16);
                unsigned o1 = (unsigned)f2bf(Cl[row][cb + 2]) | ((unsigned)f2bf(Cl[row][cb + 3]) << 16);
                unsigned o2 = (unsigned)f2bf(Cl[row][cb + 4]) | ((unsigned)f2bf(Cl[row][cb + 5]) << 16);
                unsigned o3 = (unsigned)f2bf(Cl[row][cb + 6]) | ((unsigned)f2bf(Cl[row][cb + 7]) << 16);
                uint4 o4 = {o0, o1, o2, o3};
                *(uint4*)(C + (size_t)gr * 64 + cb / 2) = o4;
            }
        } else {
            float* mu = (float*)Cv;
            float* lv = mu + (size_t)nrows * 64;
            float* dst = (c0 < 64) ? (mu + (size_t)gr * 64 + c0) : (lv + (size_t)gr * 64 + (c0 - 64));
#pragma unroll
            for (int u = 0; u < 8; ++u) {
                int cb = c0 + u * 4;
                float4 o = make_float4(Cl[row][cb + 0] + bias[cb + 0],
                                       Cl[row][cb + 1] + bias[cb + 1],
                                       Cl[row][cb + 2] + bias[cb + 2],
                                       Cl[row][cb + 3] + bias[cb + 3]);
                *(float4*)(dst + u * 4) = o;
            }
        }
    }
}

// ---------------------------------------------------------------------------

extern "C" void kernel_launch(void* const* d_in, const int* in_sizes, int n_in,
                              void* d_out, int out_size, void* d_ws, size_t ws_size,
                              hipStream_t stream) {
    const float* x   = (const float*)d_in[0];
    const int*   ei  = (const int*)d_in[1];
    const float* W1  = (const float*)d_in[2];
    const float* b1  = (const float*)d_in[3];
    const float* g1  = (const float*)d_in[4];
    const float* be1 = (const float*)d_in[5];
    const float* W2  = (const float*)d_in[6];
    const float* b2  = (const float*)d_in[7];
    const float* g2  = (const float*)d_in[8];
    const float* be2 = (const float*)d_in[9];
    const float* Wmu = (const float*)d_in[10];
    const float* bmu = (const float*)d_in[11];
    const float* Wlv = (const float*)d_in[12];
    const float* blv = (const float*)d_in[13];

    const int n = in_sizes[0] / 128;   // 100000
    const int e = in_sizes[1] / 2;     // 1600000

    const int P   = (n + PSZ - 1) / PSZ;   // 391 partitions
    const int epb = (e + NB - 1) / NB;     // 6250 edges per hist/stage block

    char* ws = (char*)d_ws;
    size_t off = 0;
    auto alloc = [&](size_t bytes) {
        void* p = ws + off;
        off = (off + bytes + 255) & ~(size_t)255;
        return p;
    };
    float*          bufH    = (float*)alloc((size_t)n * 128 * 4);     // 51.2 MB fp32 h
    unsigned*       hWb     = (unsigned*)alloc((size_t)n * 64 * 4);   // 25.6 MB bf16x2 hW
    uint2*          staged  = (uint2*)alloc((size_t)e * 8);           // 12.8 MB
    int*            csr_src = (int*)alloc((size_t)e * 4);             //  6.4 MB
    unsigned*       gh      = (unsigned*)alloc((size_t)P * NB * 4);   //  0.4 MB
    unsigned*       boffs   = (unsigned*)alloc((size_t)P * NB * 4);   //  0.4 MB
    unsigned*       tot     = (unsigned*)alloc((size_t)P * 4);
    unsigned*       gofs    = (unsigned*)alloc((size_t)P * 4);
    unsigned*       deg     = (unsigned*)alloc((size_t)n * 4);
    float*          dis     = (float*)alloc((size_t)n * 4);
    unsigned*       starts  = (unsigned*)alloc((size_t)n * 4);
    int*            eflag   = (int*)alloc(256);
    float*          sums    = (float*)alloc(256 * 4);
    float*          bnp     = (float*)alloc(256 * 4);
    unsigned short* Wt1     = (unsigned short*)alloc(16384 * 2);
    unsigned short* Wt2     = (unsigned short*)alloc(16384 * 2);
    unsigned short* Wtc     = (unsigned short*)alloc(16384 * 2);
    float*          bcat    = (float*)alloc(128 * 4);
    // ws total ~99 MB (ws_size >= ~103 MB established round 6)

    const int ab = (n + 3) / 4;
    const int gg = (n + 63) / 64;

    // prep: weights + atomic-free radix CSR build (also produces deg/dis/starts)
    prep_weights<<<192, 256, 0, stream>>>(W1, W2, Wmu, Wlv, bmu, blv, Wt1, Wt2, Wtc, bcat);
    k_edetect<<<1, 64, 0, stream>>>(ei, n, eflag);
    k_hist <<<NB, 256, 0, stream>>>(ei, eflag, gh, e, n, P, epb);
    k_scanp<<<P, 256, 0, stream>>>(gh, boffs, tot, P);
    k_scant<<<1, 512, 0, stream>>>(tot, gofs, P);
    k_stage<<<NB, 256, 0, stream>>>(ei, eflag, boffs, gofs, staged, e, n, P, epb);
    k_fill <<<P, 256, 0, stream>>>(staged, gofs, tot, csr_src, deg, dis, starts, n, P);

    // layer 1: hW1 = x@W1 -> hWb (bf16) ; h1 = agg+b1 -> bufH ; bn1
    gemm_mfma<false><<<gg, 256, 0, stream>>>(x, Wt1, nullptr, nullptr, hWb, n);
    aggregate<<<ab, 256, 0, stream>>>(hWb, csr_src, starts, deg, dis, b1, bufH, n);
    hipMemsetAsync(sums, 0, 1024, stream);
    bn_stats<<<512, 256, 0, stream>>>(bufH, sums, n);
    bn_final<<<1, 128, 0, stream>>>(sums, g1, be1, bnp, n);

    // layer 2: hW2 = bnrelu(h1)@W2 -> hWb ; h2 = agg+b2 -> bufH ; bn2
    gemm_mfma<false><<<gg, 256, 0, stream>>>(bufH, Wt2, bnp, nullptr, hWb, n);
    aggregate<<<ab, 256, 0, stream>>>(hWb, csr_src, starts, deg, dis, b2, bufH, n);
    hipMemsetAsync(sums, 0, 1024, stream);
    bn_stats<<<512, 256, 0, stream>>>(bufH, sums, n);
    bn_final<<<1, 128, 0, stream>>>(sums, g2, be2, bnp, n);

    // heads: bnrelu(h2)@[Wmu|Wlv]+[bmu|blv] -> d_out (mu||lv) directly
    gemm_mfma<true><<<gg, 256, 0, stream>>>(bufH, Wtc, bnp, bcat, d_out, n);
}

// Round 23
// 389.339 us; speedup vs baseline: 1.5410x; 1.1493x over previous
//
#include <hip/hip_runtime.h>

// ---------------------------------------------------------------------------
// StructureEncoder — MFMA bf16 GEMMs (epilogue pre-scales hW rows by dis[row],
// removing per-edge dis loads+FMAs from aggregate), CSR gather aggregation
// (bf16 hW', ILP-16), float4-vectorized BN stats, block-radix CSR build.
// ---------------------------------------------------------------------------

typedef __attribute__((ext_vector_type(8))) short bf16x8;
typedef __attribute__((ext_vector_type(4))) float f32x4;

#define NB   256        // histogram/stage blocks
#define PSZ  256        // nodes per partition
#define PMAX 512        // LDS capacity for partition arrays (P=391 for n=1e5)

__device__ inline unsigned short f2bf(float f) {
    unsigned u = __float_as_uint(f);
    unsigned r = u + 0x7FFFu + ((u >> 16) & 1u);   // RNE
    return (unsigned short)(r >> 16);
}
__device__ inline float bf2f(unsigned u16) {
    return __uint_as_float(u16 << 16);
}

__global__ void k_edetect(const int* __restrict__ ei, int n, int* __restrict__ flag) {
    if (threadIdx.x == 0 && blockIdx.x == 0) {
        int is64 = 1;
        for (int i = 0; i < 64; ++i) {
            if (ei[2 * i + 1] != 0 || (unsigned)ei[2 * i] >= (unsigned)n) { is64 = 0; break; }
        }
        *flag = is64;
    }
}

__device__ inline void load_edge(const int* __restrict__ ei, int eflag, size_t i, size_t e,
                                 int& s, int& d) {
    if (eflag) {
        s = ei[2 * i];
        d = ei[2 * e + 2 * i];
    } else {
        s = ei[i];
        d = ei[e + i];
    }
}

// ---- phase 1: per-block partition histogram gh[p][b] -----------------------

__global__ __launch_bounds__(256) void k_hist(const int* __restrict__ ei,
                                              const int* __restrict__ eflag,
                                              unsigned* __restrict__ gh,
                                              int e, int n, int P, int epb) {
    __shared__ unsigned hist[PMAX];
    int t = threadIdx.x, b = blockIdx.x;
    for (int p = t; p < P; p += 256) hist[p] = 0u;
    __syncthreads();
    int f = *eflag;
    int end = min(e, (b + 1) * epb);
    for (int i = b * epb + t; i < end; i += 256) {
        int s, d;
        load_edge(ei, f, (size_t)i, (size_t)e, s, d);
        if ((unsigned)d < (unsigned)n) atomicAdd(&hist[d >> 8], 1u);
    }
    __syncthreads();
    for (int p = t; p < P; p += 256) gh[(size_t)p * NB + b] = hist[p];
}

// ---- phase 2a: per-partition exclusive scan over blocks --------------------

__global__ __launch_bounds__(256) void k_scanp(const unsigned* __restrict__ gh,
                                               unsigned* __restrict__ boffs,
                                               unsigned* __restrict__ tot, int P) {
    __shared__ unsigned tmp[256];
    int p = blockIdx.x, t = threadIdx.x;
    unsigned v = gh[(size_t)p * NB + t];
    tmp[t] = v;
    __syncthreads();
    for (int o = 1; o < 256; o <<= 1) {
        unsigned u = (t >= o) ? tmp[t - o] : 0u;
        __syncthreads();
        tmp[t] += u;
        __syncthreads();
    }
    boffs[(size_t)p * NB + t] = tmp[t] - v;
    if (t == 255) tot[p] = tmp[255];
}

// ---- phase 2b: exclusive scan of partition totals -> gofs ------------------

__global__ void k_scant(const unsigned* __restrict__ tot,
                        unsigned* __restrict__ gofs, int P) {
    __shared__ unsigned tmp[512];
    int t = threadIdx.x;                  // 512 threads
    unsigned v = (t < P) ? tot[t] : 0u;
    tmp[t] = v;
    __syncthreads();
    for (int o = 1; o < 512; o <<= 1) {
        unsigned u = (t >= o) ? tmp[t - o] : 0u;
        __syncthreads();
        tmp[t] += u;
        __syncthreads();
    }
    if (t < P) gofs[t] = tmp[t] - v;
}

// ---- phase 3: stage edges grouped by partition (LDS cursors, no glb atomics)

__global__ __launch_bounds__(256) void k_stage(const int* __restrict__ ei,
                                               const int* __restrict__ eflag,
                                               const unsigned* __restrict__ boffs,
                                               const unsigned* __restrict__ gofs,
                                               uint2* __restrict__ staged,
                                               int e, int n, int P, int epb) {
    __shared__ unsigned cur[PMAX];
    int t = threadIdx.x, b = blockIdx.x;
    for (int p = t; p < P; p += 256) cur[p] = gofs[p] + boffs[(size_t)p * NB + b];
    __syncthreads();
    int f = *eflag;
    int end = min(e, (b + 1) * epb);
    for (int i = b * epb + t; i < end; i += 256) {
        int s, d;
        load_edge(ei, f, (size_t)i, (size_t)e, s, d);
        if ((unsigned)d >= (unsigned)n) continue;
        unsigned pos = atomicAdd(&cur[d >> 8], 1u);
        if (pos < (unsigned)e) staged[pos] = make_uint2((unsigned)s, (unsigned)d);
    }
}

// ---- phase 4: one block per partition: deg/dis/starts + csr scatter --------

__global__ __launch_bounds__(256) void k_fill(const uint2* __restrict__ staged,
                                              const unsigned* __restrict__ gofs,
                                              const unsigned* __restrict__ tot,
                                              int* __restrict__ csr_src,
                                              unsigned* __restrict__ deg,
                                              float* __restrict__ dis,
                                              unsigned* __restrict__ starts,
                                              int n, int P) {
    __shared__ unsigned h2[256], tmp[256], cur2[256];
    int p = blockIdx.x, t = threadIdx.x;
    unsigned base = gofs[p], cnt = tot[p];
    h2[t] = 0u;
    __syncthreads();
    for (unsigned i = t; i < cnt; i += 256) {
        unsigned dl = staged[base + i].y & 255u;
        atomicAdd(&h2[dl], 1u);
    }
    __syncthreads();
    unsigned cv = h2[t];
    tmp[t] = cv;
    __syncthreads();
    for (int o = 1; o < 256; o <<= 1) {
        unsigned u = (t >= o) ? tmp[t - o] : 0u;
        __syncthreads();
        tmp[t] += u;
        __syncthreads();
    }
    unsigned excl = tmp[t] - cv;
    int node = p * PSZ + t;
    if (node < n) {
        deg[node]    = cv;
        dis[node]    = rsqrtf((float)cv + 1.0f);   // degree with self loop
        starts[node] = base + excl;
    }
    cur2[t] = base + excl;
    __syncthreads();
    for (unsigned i = t; i < cnt; i += 256) {
        uint2 ed = staged[base + i];
        unsigned slot = atomicAdd(&cur2[ed.y & 255u], 1u);
        csr_src[slot] = (ed.x < (unsigned)n) ? (int)ed.x : 0;
    }
}

// ---- weight prep: Wt[c][k] = bf16(W[k][c]) for W1, W2, [Wmu|Wlv]; bcat -----

__global__ __launch_bounds__(256) void prep_weights(const float* __restrict__ W1,
                                                    const float* __restrict__ W2,
                                                    const float* __restrict__ Wmu,
                                                    const float* __restrict__ Wlv,
                                                    const float* __restrict__ bmu,
                                                    const float* __restrict__ blv,
                                                    unsigned short* __restrict__ Wt1,
                                                    unsigned short* __restrict__ Wt2,
                                                    unsigned short* __restrict__ Wtc,
                                                    float* __restrict__ bcat) {
    int idx = blockIdx.x * 256 + threadIdx.x;
    if (idx < 16384) {
        int c = idx >> 7, k = idx & 127;
        Wt1[idx] = f2bf(W1[(size_t)k * 128 + c]);
    } else if (idx < 32768) {
        int t = idx - 16384, c = t >> 7, k = t & 127;
        Wt2[t] = f2bf(W2[(size_t)k * 128 + c]);
    } else if (idx < 49152) {
        int t = idx - 32768, c = t >> 7, k = t & 127;
        float v = (c < 64) ? Wmu[(size_t)k * 64 + c] : Wlv[(size_t)k * 64 + (c - 64)];
        Wtc[t] = f2bf(v);
    }
    if (idx < 128) bcat[idx] = (idx < 64) ? bmu[idx] : blv[idx - 64];
}

// ---- aggregation (gather, pre-scaled bf16 hW', ILP-16/8/4/1) ---------------
// hW'[s] = dis[s]*hW[s] (scaled in GEMM epilogue)
// h[node] = dis[node]*( sum_e hW'[src] + hW'[node] ) + bias

__global__ __launch_bounds__(256) void aggregate(const unsigned* __restrict__ hWb,
                                                 const int* __restrict__ csr_src,
                                                 const unsigned* __restrict__ starts,
                                                 const unsigned* __restrict__ deg,
                                                 const float* __restrict__ dis,
                                                 const float* __restrict__ bias,
                                                 float* __restrict__ outh, int n) {
    int node = blockIdx.x * 4 + (threadIdx.x >> 6);
    int lane = threadIdx.x & 63;
    if (node >= n) return;
    unsigned s0 = starts[node], dn = deg[node];
    float ax = 0.f, ay = 0.f;
    unsigned j = 0;
    for (; j + 16 <= dn; j += 16) {
        int si[16]; unsigned vv[16];
#pragma unroll
        for (int q = 0; q < 16; ++q) si[q] = csr_src[s0 + j + q];
#pragma unroll
        for (int q = 0; q < 16; ++q) vv[q] = hWb[(size_t)si[q] * 64 + lane];
#pragma unroll
        for (int q = 0; q < 16; ++q) {
            ax += bf2f(vv[q] & 0xFFFFu);
            ay += bf2f(vv[q] >> 16);
        }
    }
    for (; j + 8 <= dn; j += 8) {
        int si[8]; unsigned vv[8];
#pragma unroll
        for (int q = 0; q < 8; ++q) si[q] = csr_src[s0 + j + q];
#pragma unroll
        for (int q = 0; q < 8; ++q) vv[q] = hWb[(size_t)si[q] * 64 + lane];
#pragma unroll
        for (int q = 0; q < 8; ++q) {
            ax += bf2f(vv[q] & 0xFFFFu);
            ay += bf2f(vv[q] >> 16);
        }
    }
    for (; j + 4 <= dn; j += 4) {
        int si[4]; unsigned vv[4];
#pragma unroll
        for (int q = 0; q < 4; ++q) si[q] = csr_src[s0 + j + q];
#pragma unroll
        for (int q = 0; q < 4; ++q) vv[q] = hWb[(size_t)si[q] * 64 + lane];
#pragma unroll
        for (int q = 0; q < 4; ++q) {
            ax += bf2f(vv[q] & 0xFFFFu);
            ay += bf2f(vv[q] >> 16);
        }
    }
    for (; j < dn; ++j) {
        unsigned v = hWb[(size_t)csr_src[s0 + j] * 64 + lane];
        ax += bf2f(v & 0xFFFFu);
        ay += bf2f(v >> 16);
    }
    unsigned vs = hWb[(size_t)node * 64 + lane];
    ax += bf2f(vs & 0xFFFFu);
    ay += bf2f(vs >> 16);
    float dii = dis[node];
    float rx = fmaf(dii, ax, bias[lane * 2]);
    float ry = fmaf(dii, ay, bias[lane * 2 + 1]);
    *(float2*)(outh + (size_t)node * 128 + lane * 2) = make_float2(rx, ry);
}

// ---- BatchNorm statistics (float4-vectorized) ------------------------------

__global__ __launch_bounds__(256) void bn_stats(const float* __restrict__ h,
                                                float* __restrict__ sums, int n) {
    int t  = threadIdx.x;
    int q  = t & 31;          // channel quad (channels q*4 .. q*4+3)
    int sl = t >> 5;          // row slice 0..7
    float s0 = 0.f, s1 = 0.f, s2 = 0.f, s3 = 0.f;
    float q0 = 0.f, q1 = 0.f, q2 = 0.f, q3 = 0.f;
    for (int r = blockIdx.x * 8 + sl; r < n; r += gridDim.x * 8) {
        float4 v = *(const float4*)(h + (size_t)r * 128 + q * 4);
        s0 += v.x; q0 = fmaf(v.x, v.x, q0);
        s1 += v.y; q1 = fmaf(v.y, v.y, q1);
        s2 += v.z; q2 = fmaf(v.z, v.z, q2);
        s3 += v.w; q3 = fmaf(v.w, v.w, q3);
    }
    __shared__ float sh[256][8];
    sh[t][0] = s0; sh[t][1] = s1; sh[t][2] = s2; sh[t][3] = s3;
    sh[t][4] = q0; sh[t][5] = q1; sh[t][6] = q2; sh[t][7] = q3;
    __syncthreads();
    if (t < 128) {
        int cq = t >> 2, ce = t & 3;
        float a = 0.f, b = 0.f;
#pragma unroll
        for (int s8 = 0; s8 < 8; ++s8) {
            a += sh[s8 * 32 + cq][ce];
            b += sh[s8 * 32 + cq][4 + ce];
        }
        atomicAdd(&sums[t], a);
        atomicAdd(&sums[128 + t], b);
    }
}

__global__ void bn_final(const float* __restrict__ sums, const float* __restrict__ g,
                         const float* __restrict__ be, float* __restrict__ bnp, int n) {
    int c = threadIdx.x;                            // 128 threads
    float inv_n = 1.0f / (float)n;
    float mean = sums[c] * inv_n;
    float var  = sums[128 + c] * inv_n - mean * mean;
    float sc   = g[c] * rsqrtf(var + 1e-5f);
    bnp[c]       = sc;
    bnp[128 + c] = be[c] - mean * sc;
}

// ---- MFMA GEMM: C[M,128] = bnrelu(A)[M,128] @ W[128,128], A fp32 -----------
// !HEAD: epilogue scales row r by disv[r] before bf16 pack (hW' = dis*hW).

template <bool HEAD>
__global__ __launch_bounds__(256, 4) void gemm_mfma(const float* __restrict__ A,
                                                    const unsigned short* __restrict__ Wt,
                                                    const float* __restrict__ bnp,
                                                    const float* __restrict__ bias,
                                                    const float* __restrict__ disv,
                                                    void* __restrict__ Cv, int nrows) {
    __shared__ float Cl[64][130];
    __shared__ float bnsc[128], bnsh[128];

    const int tid  = threadIdx.x;
    const int lane = tid & 63;
    const int wv   = tid >> 6;
    const int rowbase = blockIdx.x * 64;
    const bool has_bn = (bnp != nullptr);
    if (has_bn && tid < 128) {
        bnsc[tid] = bnp[tid];
        bnsh[tid] = bnp[128 + tid];
    }
    __syncthreads();

    const int ar = rowbase + wv * 16 + (lane & 15);
    const int kg = (lane >> 4) * 8;
    const int bc = lane & 15;

    f32x4 acc[8];
#pragma unroll
    for (int t = 0; t < 8; ++t) acc[t] = {0.f, 0.f, 0.f, 0.f};

#pragma unroll
    for (int k0 = 0; k0 < 128; k0 += 32) {
        float va[8];
        if (ar < nrows) {
            float4 a0 = *(const float4*)(A + (size_t)ar * 128 + k0 + kg);
            float4 a1 = *(const float4*)(A + (size_t)ar * 128 + k0 + kg + 4);
            va[0] = a0.x; va[1] = a0.y; va[2] = a0.z; va[3] = a0.w;
            va[4] = a1.x; va[5] = a1.y; va[6] = a1.z; va[7] = a1.w;
        } else {
#pragma unroll
            for (int i = 0; i < 8; ++i) va[i] = 0.f;
        }
        if (has_bn) {
#pragma unroll
            for (int i = 0; i < 8; ++i) {
                int k = k0 + kg + i;
                va[i] = fmaxf(0.f, fmaf(va[i], bnsc[k], bnsh[k]));
            }
        }
        bf16x8 af;
#pragma unroll
        for (int i = 0; i < 8; ++i) af[i] = (short)f2bf(va[i]);

#pragma unroll
        for (int ct = 0; ct < 8; ++ct) {
            bf16x8 bf = *(const bf16x8*)(Wt + (size_t)(ct * 16 + bc) * 128 + k0 + kg);
            acc[ct] = __builtin_amdgcn_mfma_f32_16x16x32_bf16(af, bf, acc[ct], 0, 0, 0);
        }
    }

    const int lr = wv * 16 + ((lane >> 4) << 2);
#pragma unroll
    for (int ct = 0; ct < 8; ++ct)
#pragma unroll
        for (int r = 0; r < 4; ++r)
            Cl[lr + r][ct * 16 + bc] = acc[ct][r];
    __syncthreads();

    const int row = tid >> 2;
    const int c0  = (tid & 3) * 32;
    const int gr  = rowbase + row;
    if (gr < nrows) {
        if (!HEAD) {
            float dsc = disv[gr];        // pre-scale hW row by dis[row]
            unsigned* C = (unsigned*)Cv;
#pragma unroll
            for (int u = 0; u < 4; ++u) {
                int cb = c0 + u * 8;
                unsigned o0 = (unsigned)f2bf(Cl[row][cb + 0] * dsc) | ((unsigned)f2bf(Cl[row][cb + 1] * dsc) << 16);
                unsigned o1 = (unsigned)f2bf(Cl[row][cb + 2] * dsc) | ((unsigned)f2bf(Cl[row][cb + 3] * dsc) << 16);
                unsigned o2 = (unsigned)f2bf(Cl[row][cb + 4] * dsc) | ((unsigned)f2bf(Cl[row][cb + 5] * dsc) << 16);
                unsigned o3 = (unsigned)f2bf(Cl[row][cb + 6] * dsc) | ((unsigned)f2bf(Cl[row][cb + 7] * dsc) << 16);
                uint4 o4 = {o0, o1, o2, o3};
                *(uint4*)(C + (size_t)gr * 64 + cb / 2) = o4;
            }
        } else {
            float* mu = (float*)Cv;
            float* lv = mu + (size_t)nrows * 64;
            float* dst = (c0 < 64) ? (mu + (size_t)gr * 64 + c0) : (lv + (size_t)gr * 64 + (c0 - 64));
#pragma unroll
            for (int u = 0; u < 8; ++u) {
                int cb = c0 + u * 4;
                float4 o = make_float4(Cl[row][cb + 0] + bias[cb + 0],
                                       Cl[row][cb + 1] + bias[cb + 1],
                                       Cl[row][cb + 2] + bias[cb + 2],
                                       Cl[row][cb + 3] + bias[cb + 3]);
                *(float4*)(dst + u * 4) = o;
            }
        }
    }
}

// ---------------------------------------------------------------------------

extern "C" void kernel_launch(void* const* d_in, const int* in_sizes, int n_in,
                              void* d_out, int out_size, void* d_ws, size_t ws_size,
                              hipStream_t stream) {
    const float* x   = (const float*)d_in[0];
    const int*   ei  = (const int*)d_in[1];
    const float* W1  = (const float*)d_in[2];
    const float* b1  = (const float*)d_in[3];
    const float* g1  = (const float*)d_in[4];
    const float* be1 = (const float*)d_in[5];
    const float* W2  = (const float*)d_in[6];
    const float* b2  = (const float*)d_in[7];
    const float* g2  = (const float*)d_in[8];
    const float* be2 = (const float*)d_in[9];
    const float* Wmu = (const float*)d_in[10];
    const float* bmu = (const float*)d_in[11];
    const float* Wlv = (const float*)d_in[12];
    const float* blv = (const float*)d_in[13];

    const int n = in_sizes[0] / 128;   // 100000
    const int e = in_sizes[1] / 2;     // 1600000

    const int P   = (n + PSZ - 1) / PSZ;   // 391 partitions
    const int epb = (e + NB - 1) / NB;     // 6250 edges per hist/stage block

    char* ws = (char*)d_ws;
    size_t off = 0;
    auto alloc = [&](size_t bytes) {
        void* p = ws + off;
        off = (off + bytes + 255) & ~(size_t)255;
        return p;
    };
    float*          bufH    = (float*)alloc((size_t)n * 128 * 4);     // 51.2 MB fp32 h
    unsigned*       hWb     = (unsigned*)alloc((size_t)n * 64 * 4);   // 25.6 MB bf16x2 hW'
    uint2*          staged  = (uint2*)alloc((size_t)e * 8);           // 12.8 MB
    int*            csr_src = (int*)alloc((size_t)e * 4);             //  6.4 MB
    unsigned*       gh      = (unsigned*)alloc((size_t)P * NB * 4);   //  0.4 MB
    unsigned*       boffs   = (unsigned*)alloc((size_t)P * NB * 4);   //  0.4 MB
    unsigned*       tot     = (unsigned*)alloc((size_t)P * 4);
    unsigned*       gofs    = (unsigned*)alloc((size_t)P * 4);
    unsigned*       deg     = (unsigned*)alloc((size_t)n * 4);
    float*          dis     = (float*)alloc((size_t)n * 4);
    unsigned*       starts  = (unsigned*)alloc((size_t)n * 4);
    int*            eflag   = (int*)alloc(256);
    float*          sums    = (float*)alloc(256 * 4);
    float*          bnp     = (float*)alloc(256 * 4);
    unsigned short* Wt1     = (unsigned short*)alloc(16384 * 2);
    unsigned short* Wt2     = (unsigned short*)alloc(16384 * 2);
    unsigned short* Wtc     = (unsigned short*)alloc(16384 * 2);
    float*          bcat    = (float*)alloc(128 * 4);
    // ws total ~99 MB

    const int ab = (n + 3) / 4;
    const int gg = (n + 63) / 64;

    // prep: weights + atomic-free radix CSR build (produces deg/dis/starts)
    prep_weights<<<192, 256, 0, stream>>>(W1, W2, Wmu, Wlv, bmu, blv, Wt1, Wt2, Wtc, bcat);
    k_edetect<<<1, 64, 0, stream>>>(ei, n, eflag);
    k_hist <<<NB, 256, 0, stream>>>(ei, eflag, gh, e, n, P, epb);
    k_scanp<<<P, 256, 0, stream>>>(gh, boffs, tot, P);
    k_scant<<<1, 512, 0, stream>>>(tot, gofs, P);
    k_stage<<<NB, 256, 0, stream>>>(ei, eflag, boffs, gofs, staged, e, n, P, epb);
    k_fill <<<P, 256, 0, stream>>>(staged, gofs, tot, csr_src, deg, dis, starts, n, P);

    // layer 1: hW1' = dis*(x@W1) -> hWb ; h1 = agg+b1 -> bufH ; bn1
    gemm_mfma<false><<<gg, 256, 0, stream>>>(x, Wt1, nullptr, nullptr, dis, hWb, n);
    aggregate<<<ab, 256, 0, stream>>>(hWb, csr_src, starts, deg, dis, b1, bufH, n);
    hipMemsetAsync(sums, 0, 1024, stream);
    bn_stats<<<512, 256, 0, stream>>>(bufH, sums, n);
    bn_final<<<1, 128, 0, stream>>>(sums, g1, be1, bnp, n);

    // layer 2: hW2' = dis*(bnrelu(h1)@W2) -> hWb ; h2 = agg+b2 -> bufH ; bn2
    gemm_mfma<false><<<gg, 256, 0, stream>>>(bufH, Wt2, bnp, nullptr, dis, hWb, n);
    aggregate<<<ab, 256, 0, stream>>>(hWb, csr_src, starts, deg, dis, b2, bufH, n);
    hipMemsetAsync(sums, 0, 1024, stream);
    bn_stats<<<512, 256, 0, stream>>>(bufH, sums, n);
    bn_final<<<1, 128, 0, stream>>>(sums, g2, be2, bnp, n);

    // heads: bnrelu(h2)@[Wmu|Wlv]+[bmu|blv] -> d_out (mu||lv) directly
    gemm_mfma<true><<<gg, 256, 0, stream>>>(bufH, Wtc, bnp, bcat, nullptr, d_out, n);
}